// Round 1
// baseline (232.636 us; speedup 1.0000x reference)
//
#include <hip/hip_runtime.h>

// Sepconv: out[b,c,y,x] = sum_{i,j} In[b,c,y*F+i,x*F+j] * V[b,i,y,x] * H[b,j,y,x]
// B=8, C=3, F=5, HO=WO=256. All fp32. Memory-bound (~180 MB traffic, ~29 us floor).

#define Bsz 8
#define Csz 3
#define Fsz 5
#define HOsz 256
#define WOsz 256

__global__ __launch_bounds__(256) void sepconv_kernel(
    const float* __restrict__ in,   // [B,C,HO*F,WO*F]
    const float* __restrict__ V,    // [B,F,HO,WO]
    const float* __restrict__ Hh,   // [B,F,HO,WO]
    float* __restrict__ out)        // [B,C,HO,WO]
{
    const int idx = blockIdx.x * blockDim.x + threadIdx.x;
    // idx = ((b*C + c)*HO + y)*WO + x ; HO=WO=256 -> shifts
    const int x  = idx & (WOsz - 1);
    const int y  = (idx >> 8) & (HOsz - 1);
    const int bc = idx >> 16;          // b*C + c, 0..23
    if (bc >= Bsz * Csz) return;
    const int c = bc % Csz;
    const int b = bc / Csz;

    constexpr int W = WOsz * Fsz;      // 1280
    constexpr int Hfull = HOsz * Fsz;  // 1280
    constexpr int PLANE = HOsz * WOsz; // 65536

    // Load the 5 vertical + 5 horizontal weights (coalesced: stride-1 in x)
    const float* vp = V  + (b * Fsz * PLANE) + y * WOsz + x;
    const float* hp = Hh + (b * Fsz * PLANE) + y * WOsz + x;
    float v[Fsz], h[Fsz];
#pragma unroll
    for (int i = 0; i < Fsz; ++i) {
        v[i] = vp[i * PLANE];
        h[i] = hp[i * PLANE];
    }

    // Patch base: rows y*F..y*F+4, cols x*F..x*F+4
    const float* ip = in + ((size_t)(b * Csz + c) * Hfull + y * Fsz) * W + x * Fsz;

    float acc = 0.f;
#pragma unroll
    for (int i = 0; i < Fsz; ++i) {
        float rs = 0.f;
#pragma unroll
        for (int j = 0; j < Fsz; ++j)
            rs = fmaf(ip[(size_t)i * W + j], h[j], rs);
        acc = fmaf(rs, v[i], acc);
    }
    out[idx] = acc;
}

extern "C" void kernel_launch(void* const* d_in, const int* in_sizes, int n_in,
                              void* d_out, int out_size, void* d_ws, size_t ws_size,
                              hipStream_t stream) {
    const float* in = (const float*)d_in[0];
    const float* V  = (const float*)d_in[1];
    const float* Hh = (const float*)d_in[2];
    float* out = (float*)d_out;

    const int total = Bsz * Csz * HOsz * WOsz;  // 1,572,864
    const int block = 256;
    const int grid = (total + block - 1) / block;  // 6144
    sepconv_kernel<<<grid, block, 0, stream>>>(in, V, Hh, out);
}